// Round 8
// baseline (7739.608 us; speedup 1.0000x reference)
//
#include <hip/hip_runtime.h>
#include <cstdint>
#include <cstddef>
#include <string.h>

typedef __bf16 bf16;
typedef bf16 bf16x4 __attribute__((ext_vector_type(4)));
typedef bf16 bf16x8 __attribute__((ext_vector_type(8)));
typedef float f32x4 __attribute__((ext_vector_type(4)));
typedef unsigned long long u64;

#define B_   64
#define T_   512
#define I_   1024
#define H_   1024
#define BT_  32768
#define NBL  64    // lstm blocks
#define NJ   16    // hidden units per lstm block

// ---- ws layout (bytes) ----
#define WS_XBF   ((size_t)0)              // x as bf16 [32768][1024]            : 67108864
#define WS_WXP   ((size_t)67108864)       // Wx^T bf16 [4096][1024]             : 8388608
#define WS_WHP   ((size_t)75497472)       // Wh packed bf16 [64][128][64][8]    : 8388608
#define WS_XG    ((size_t)83886080)       // xg bf16 [512][64][64][64]          : 268435456
#define WS_HB    ((size_t)352321536)      // h dbuf bf16 [2][64][1024]          : 262144
#define WS_ARR   ((size_t)352583680)      // flags u32[4 r16][64 blk][2 nh]     : 8192
#define WS_NEED  ((size_t)352600064)

#define GLD_LDS16(gptr, lptr) \
  __builtin_amdgcn_global_load_lds((const __attribute__((address_space(1))) void*)(gptr), \
                                   (__attribute__((address_space(3))) void*)(lptr), 16, 0, 0)

__device__ __forceinline__ float sigmoidf_(float x) { return 1.0f / (1.0f + __expf(-x)); }
// branch-free tanh: 1 - 2/(e^{2x}+1); saturates correctly for |x| large (no NaN).
__device__ __forceinline__ float tanhf_(float x) { float e = __expf(2.0f * x); return 1.0f - 2.0f / (e + 1.0f); }
__device__ __forceinline__ float lo2f(unsigned u) { unsigned v = u << 16; float f; memcpy(&f, &v, 4); return f; }
__device__ __forceinline__ float hi2f(unsigned u) { unsigned v = u & 0xffff0000u; float f; memcpy(&f, &v, 4); return f; }
__device__ __forceinline__ unsigned short b2s(bf16 h) { unsigned short s; memcpy(&s, &h, 2); return s; }

// 4x4 transpose across the 4 lanes of a quad (lane&3 = col; f32x4 regs = rows).
// Post: lane&3 = row, regs = cols.  Verified: M2[r]@lane c == M[c][r].
__device__ __forceinline__ f32x4 quad_transpose(f32x4 v, int lane) {
  f32x4 m1, m2;
  float s10 = __shfl_xor(v[1], 1);
  float s11 = __shfl_xor(v[0], 1);
  float s12 = __shfl_xor(v[3], 1);
  float s13 = __shfl_xor(v[2], 1);
  bool e1 = (lane & 1) == 0;
  m1[0] = e1 ? v[0] : s10;
  m1[1] = e1 ? s11 : v[1];
  m1[2] = e1 ? v[2] : s12;
  m1[3] = e1 ? s13 : v[3];
  float s20 = __shfl_xor(m1[2], 2);
  float s21 = __shfl_xor(m1[3], 2);
  float s22 = __shfl_xor(m1[0], 2);
  float s23 = __shfl_xor(m1[1], 2);
  bool e2 = (lane & 2) == 0;
  m2[0] = e2 ? m1[0] : s20;
  m2[1] = e2 ? m1[1] : s21;
  m2[2] = e2 ? s22 : m1[2];
  m2[3] = e2 ? s23 : m1[3];
  return m2;
}

// ---------------- pack kernels ----------------

__global__ __launch_bounds__(256) void k_cvt_x(const float4* __restrict__ in,
                                               bf16* __restrict__ out, int n4) {
  int i = blockIdx.x * blockDim.x + threadIdx.x;
  int stride = gridDim.x * blockDim.x;
  for (; i < n4; i += stride) {
    float4 v = in[i];
    bf16x4 r = { (bf16)v.x, (bf16)v.y, (bf16)v.z, (bf16)v.w };
    *(bf16x4*)(out + (size_t)i * 4) = r;
  }
}

// Wx^T: wxp[(gate*1024 + n)][k] = W[k][n]   (32x32 LDS tile transpose)
__global__ __launch_bounds__(256) void k_pack_wx(const float* __restrict__ W,
                                                 bf16* __restrict__ wxp, int gate) {
  __shared__ bf16 tile[32][33];
  int bx = blockIdx.x & 31, by = blockIdx.x >> 5;
  int tx = threadIdx.x & 31, ty = threadIdx.x >> 5;
  int k0 = by * 32, n0 = bx * 32;
  for (int r = 0; r < 32; r += 8)
    tile[ty + r][tx] = (bf16)W[(size_t)(k0 + ty + r) * H_ + n0 + tx];
  __syncthreads();
  for (int r = 0; r < 32; r += 8)
    wxp[(size_t)(gate * H_ + n0 + ty + r) * I_ + k0 + tx] = tile[tx][ty + r];
}

// Wh packed: whp[blk][k>>3][c][k&7] = W[k][u],  blk = u>>4, c = (u&15)*4 + gate
__global__ __launch_bounds__(256) void k_pack_wh(const float* __restrict__ W,
                                                 bf16* __restrict__ whp, int gate) {
  __shared__ bf16 tile[32][33];
  int bx = blockIdx.x & 31, by = blockIdx.x >> 5;
  int tx = threadIdx.x & 31, ty = threadIdx.x >> 5;
  int k0 = by * 32, u0 = bx * 32;
  for (int r = 0; r < 32; r += 8)
    tile[ty + r][tx] = (bf16)W[(size_t)(k0 + ty + r) * H_ + u0 + tx];
  __syncthreads();
  for (int r = 0; r < 32; r += 8) {
    int u = u0 + ty + r;
    int k = k0 + tx;
    size_t addr = ((size_t)(u >> 4) * 128 + (k >> 3)) * 512 +
                  (size_t)((u & 15) * 4 + gate) * 8 + (k & 7);
    whp[addr] = tile[tx][ty + r];
  }
}

// ---------------- phase 1: xg = x @ Wx  (bf16 MFMA, m97-style) ----------------
__global__ __launch_bounds__(256) void k_gemm_xg(const bf16* __restrict__ A,
                                                 const bf16* __restrict__ Bt,
                                                 bf16* __restrict__ xg) {
  __shared__ bf16 As[128 * 64];
  __shared__ bf16 Bs[128 * 64];
  int bid = blockIdx.x;
  int bm = bid >> 5, bn = bid & 31;
  int m0 = bm * 128, n0 = bn * 128;
  int tid = threadIdx.x, lane = tid & 63, w = tid >> 6;
  int lr = lane & 15, lk = lane >> 4;
  int sr = lane >> 3, sk = (lane & 7) * 8;
  int wm = (w >> 1) * 64, wn = (w & 1) * 64;
  f32x4 acc[4][4] = {};

  for (int k0 = 0; k0 < 1024; k0 += 64) {
    __syncthreads();
    for (int i = 0; i < 4; ++i) {
      int idx = w * 4 + i;
      const bf16* ga = A + (size_t)(m0 + idx * 8 + sr) * 1024 + k0 + sk;
      GLD_LDS16(ga, &As[idx * 512]);
      const bf16* gb = Bt + (size_t)(n0 + idx * 8 + sr) * 1024 + k0 + sk;
      GLD_LDS16(gb, &Bs[idx * 512]);
    }
    asm volatile("s_waitcnt vmcnt(0)" ::: "memory");
    __syncthreads();
#pragma unroll
    for (int kk = 0; kk < 64; kk += 32) {
      bf16x8 af[4], bfr[4];
#pragma unroll
      for (int i = 0; i < 4; ++i)
        af[i] = *(const bf16x8*)&As[(wm + i * 16 + lr) * 64 + kk + lk * 8];
#pragma unroll
      for (int j = 0; j < 4; ++j)
        bfr[j] = *(const bf16x8*)&Bs[(wn + j * 16 + lr) * 64 + kk + lk * 8];
#pragma unroll
      for (int i = 0; i < 4; ++i)
#pragma unroll
        for (int j = 0; j < 4; ++j)
          acc[i][j] = __builtin_amdgcn_mfma_f32_16x16x32_bf16(af[i], bfr[j], acc[i][j], 0, 0, 0);
    }
  }
  // epilogue: scatter into xg[t][blk][b][c],  blk = u>>4, c = (u&15)*4 + g
#pragma unroll
  for (int i = 0; i < 4; ++i) {
#pragma unroll
    for (int j = 0; j < 4; ++j) {
      int n = n0 + wn + j * 16 + lr;
      int u = n & 1023, g = n >> 10;
      int blk = u >> 4, c = (u & 15) * 4 + g;
      int mb = m0 + wm + i * 16 + lk * 4;
#pragma unroll
      for (int r = 0; r < 4; ++r) {
        int m = mb + r;
        int t = m & 511, bb = m >> 9;
        xg[(((size_t)t * NBL + blk) * B_ + bb) * 64 + c] = (bf16)acc[i][j][r];
      }
    }
  }
}

// ---------------- phase 2: persistent LSTM scan, zero-syncthreads dataflow ----------------
// 64 blocks x 512 threads. Block owns 16 units. Wave = (r16 rowgrp of 16 rows, nh N-half);
// each wave does FULL K=1024 for its 16 rows x 32 gate-cols -> complete gate sums in acc,
// no cross-wave reduction, no __syncthreads in steady state. Unit-major col packing
// (c = u*4+gate) + 4-lane quad transpose puts (row, unit, 4 gates) in one lane.
// 4 independent row-chains; per-wave flags armed after per-wave vmcnt-0 drain.
__global__ __launch_bounds__(512) void k_lstm(const bf16* __restrict__ xg,
                                              const bf16* __restrict__ whp,
                                              bf16* hb,              // [2][64][1024]
                                              float* __restrict__ out,
                                              unsigned* arr,         // [4 r16][64 blk][2 nh] u32
                                              const float* __restrict__ bii, const float* __restrict__ bhi,
                                              const float* __restrict__ bif, const float* __restrict__ bhf,
                                              const float* __restrict__ big, const float* __restrict__ bhg,
                                              const float* __restrict__ bio, const float* __restrict__ bho) {
  __shared__ bf16 whl[65536];          // 128 KB: [k>>3][c][k&7]
  int blk = blockIdx.x;
  int tid = threadIdx.x;
  int lane = tid & 63, w = tid >> 6;
  int r16 = w >> 1, nh = w & 1;
  int lr = lane & 15, lk = lane >> 4;

  {  // stage Wh slice: 128KB contiguous
    const bf16* src = whp + (size_t)blk * 65536;
#pragma unroll
    for (int i = 0; i < 16; ++i)
      *(bf16x8*)&whl[(size_t)(i * 512 + tid) * 8] = *(const bf16x8*)&src[(size_t)(i * 512 + tid) * 8];
  }

  // post-transpose per-lane ownership: (row, 2 units, all 4 gates each)
  int prow = (lane >> 4) * 4 + (lane & 3);        // row within rowgrp
  int grow = r16 * 16 + prow;                     // global batch row
  int ul0 = (nh * 2 + 0) * 4 + ((lane & 15) >> 2);  // unit-in-block, nt=0
  int ul1 = (nh * 2 + 1) * 4 + ((lane & 15) >> 2);  // unit-in-block, nt=1
  int ug0 = blk * NJ + ul0, ug1 = blk * NJ + ul1;
  f32x4 bias0 = { bii[ug0] + bhi[ug0], bif[ug0] + bhf[ug0],
                  big[ug0] + bhg[ug0], bio[ug0] + bho[ug0] };
  f32x4 bias1 = { bii[ug1] + bhi[ug1], bif[ug1] + bhf[ug1],
                  big[ug1] + bhg[ug1], bio[ug1] + bho[ug1] };
  float cs0 = 0.f, cs1 = 0.f;

  const char* hb_c = (const char*)hb;
  const char* flg = (const char*)arr;
  __syncthreads();  // whl ready (only barrier in the kernel)

  for (int t = 0; t < T_; ++t) {
    // ---- poll: both nh flags of all 64 blocks at my rowgrp >= t ----
    if (t > 0) {
      const char* fp = flg + ((size_t)r16 * 64 + lane) * 8;
      u64 fv; int cap = 0;
      bool ok;
      do {
        asm volatile("global_load_dwordx2 %0, %1, off sc0 sc1\n\ts_waitcnt vmcnt(0)"
                     : "=v"(fv) : "v"(fp) : "memory");
        unsigned f0 = (unsigned)fv, f1 = (unsigned)(fv >> 32);
        ok = (f0 >= (unsigned)t) && (f1 >= (unsigned)t);
      } while (!__all((int)ok) && ++cap < 300000);
      __builtin_amdgcn_sched_barrier(0);
    }

    // ---- issue 32 A-loads (full K for my 16 rows), then 2 xg loads ----
    bf16x8 af[32];
    const char* hbase = hb_c + (size_t)(t & 1) * 131072 +
                        (size_t)(r16 * 16 + lr) * 2048 + (size_t)lk * 16;
#pragma unroll
    for (int i = 0; i < 32; ++i)
      asm volatile("global_load_dwordx4 %0, %1, off sc0 sc1"
                   : "=v"(af[i]) : "v"(hbase + (size_t)i * 64));
    u64 xq0, xq1;
    {
      const char* xb = (const char*)xg + ((((size_t)t * NBL + blk) * B_ + grow) * 64) * 2;
      asm volatile("global_load_dwordx2 %0, %1, off" : "=v"(xq0) : "v"(xb + ul0 * 8));
      asm volatile("global_load_dwordx2 %0, %1, off" : "=v"(xq1) : "v"(xb + ul1 * 8));
    }

    // ---- MFMA: 32 kg x 2 nt, vmcnt-gated groups of 8 kg (34 loads in flight) ----
    f32x4 acc0 = {}, acc1 = {};
#define MFMA_GRP(G)                                                                     \
    _Pragma("unroll")                                                                   \
    for (int ii = 0; ii < 8; ++ii) {                                                    \
      int i = (G) * 8 + ii;                                                             \
      bf16x8 b0 = *(const bf16x8*)&whl[((i * 4 + lk) * 64 + (nh * 2 + 0) * 16 + lr) * 8]; \
      bf16x8 b1 = *(const bf16x8*)&whl[((i * 4 + lk) * 64 + (nh * 2 + 1) * 16 + lr) * 8]; \
      acc0 = __builtin_amdgcn_mfma_f32_16x16x32_bf16(af[i], b0, acc0, 0, 0, 0);         \
      acc1 = __builtin_amdgcn_mfma_f32_16x16x32_bf16(af[i], b1, acc1, 0, 0, 0);         \
    }
    asm volatile("s_waitcnt vmcnt(26)" ::: "memory");
    __builtin_amdgcn_sched_barrier(0);
    MFMA_GRP(0)
    asm volatile("s_waitcnt vmcnt(18)" ::: "memory");
    __builtin_amdgcn_sched_barrier(0);
    MFMA_GRP(1)
    asm volatile("s_waitcnt vmcnt(10)" ::: "memory");
    __builtin_amdgcn_sched_barrier(0);
    MFMA_GRP(2)
    asm volatile("s_waitcnt vmcnt(2)" ::: "memory");
    __builtin_amdgcn_sched_barrier(0);
    MFMA_GRP(3)
#undef MFMA_GRP
    asm volatile("s_waitcnt vmcnt(0)" ::: "memory");   // xg landed
    __builtin_amdgcn_sched_barrier(0);

    // ---- quad transpose: lane gets (prow, unit, 4 gates) in regs ----
    f32x4 g0 = quad_transpose(acc0, lane);
    f32x4 g1 = quad_transpose(acc1, lane);

    // ---- gates + state update (2 units per lane, all in registers) ----
    unsigned x0l = (unsigned)xq0, x0h = (unsigned)(xq0 >> 32);
    unsigned x1l = (unsigned)xq1, x1h = (unsigned)(xq1 >> 32);
    float gi0 = g0[0] + lo2f(x0l) + bias0[0];
    float gf0 = g0[1] + hi2f(x0l) + bias0[1];
    float gg0 = g0[2] + lo2f(x0h) + bias0[2];
    float go0 = g0[3] + hi2f(x0h) + bias0[3];
    float gi1 = g1[0] + lo2f(x1l) + bias1[0];
    float gf1 = g1[1] + hi2f(x1l) + bias1[1];
    float gg1 = g1[2] + lo2f(x1h) + bias1[2];
    float go1 = g1[3] + hi2f(x1h) + bias1[3];
    cs0 = sigmoidf_(gf0) * cs0 + sigmoidf_(gi0) * tanhf_(gg0);
    cs1 = sigmoidf_(gf1) * cs1 + sigmoidf_(gi1) * tanhf_(gg1);
    float hv0 = sigmoidf_(go0) * tanhf_(cs0);
    float hv1 = sigmoidf_(go1) * tanhf_(cs1);

    if (t == T_ - 1) {
      out[(size_t)grow * H_ + ug0] = hv0;
      out[(size_t)grow * H_ + ug1] = hv1;
      out[(size_t)B_ * H_ + (size_t)grow * H_ + ug0] = cs0;
      out[(size_t)B_ * H_ + (size_t)grow * H_ + ug1] = cs1;
      break;
    }

    // ---- publish h(t+1): two 2B stores to coherence point ----
    {
      unsigned hb0 = (unsigned)b2s((bf16)hv0);
      unsigned hb1 = (unsigned)b2s((bf16)hv1);
      const char* hn = hb_c + (size_t)((t + 1) & 1) * 131072 + (size_t)grow * 2048;
      asm volatile("global_store_short %0, %1, off sc0 sc1" :: "v"(hn + ug0 * 2), "v"(hb0) : "memory");
      asm volatile("global_store_short %0, %1, off sc0 sc1" :: "v"(hn + ug1 * 2), "v"(hb1) : "memory");
    }

    // ---- per-wave drain + arm own flag (no block-wide sync) ----
    asm volatile("s_waitcnt vmcnt(0)" ::: "memory");
    if (lane == 0) {
      unsigned tv = (unsigned)(t + 1);
      const char* fa = flg + ((size_t)r16 * 64 + blk) * 8 + nh * 4;
      asm volatile("global_store_dword %0, %1, off sc0 sc1" :: "v"(fa), "v"(tv) : "memory");
    }
  }
}

// ---------------- launcher ----------------

extern "C" void kernel_launch(void* const* d_in, const int* in_sizes, int n_in,
                              void* d_out, int out_size, void* d_ws, size_t ws_size,
                              hipStream_t stream) {
  if (ws_size < WS_NEED) return;

  const float* x = (const float*)d_in[0];
  const float* W_ii = (const float*)d_in[1];
  const float* W_hi = (const float*)d_in[2];
  const float* W_if = (const float*)d_in[3];
  const float* W_hf = (const float*)d_in[4];
  const float* W_ig = (const float*)d_in[5];
  const float* W_hg = (const float*)d_in[6];
  const float* W_io = (const float*)d_in[7];
  const float* W_ho = (const float*)d_in[8];
  const float* b_ii = (const float*)d_in[9];
  const float* b_hi = (const float*)d_in[10];
  const float* b_if = (const float*)d_in[11];
  const float* b_hf = (const float*)d_in[12];
  const float* b_ig = (const float*)d_in[13];
  const float* b_hg = (const float*)d_in[14];
  const float* b_io = (const float*)d_in[15];
  const float* b_ho = (const float*)d_in[16];

  char* ws = (char*)d_ws;
  bf16* xbf = (bf16*)(ws + WS_XBF);
  bf16* wxp = (bf16*)(ws + WS_WXP);
  bf16* whp = (bf16*)(ws + WS_WHP);
  bf16* xgp = (bf16*)(ws + WS_XG);
  bf16* hbp = (bf16*)(ws + WS_HB);
  unsigned* arrp = (unsigned*)(ws + WS_ARR);
  float* outp = (float*)d_out;

  // zero h0 buffers + flags (contiguous region)
  hipMemsetAsync(ws + WS_HB, 0, 262144 + 8192, stream);

  // pack
  k_cvt_x<<<2048, 256, 0, stream>>>((const float4*)x, xbf, BT_ * I_ / 4);
  const float* wx_g[4] = {W_ii, W_if, W_ig, W_io};
  const float* wh_g[4] = {W_hi, W_hf, W_hg, W_ho};
  for (int g = 0; g < 4; ++g) {
    k_pack_wx<<<1024, 256, 0, stream>>>(wx_g[g], wxp, g);
    k_pack_wh<<<1024, 256, 0, stream>>>(wh_g[g], whp, g);
  }

  // phase 1 GEMM
  k_gemm_xg<<<dim3(256 * 32), 256, 0, stream>>>(xbf, wxp, xgp);

  // phase 2 cooperative scan
  void* args[] = {
      (void*)&xgp, (void*)&whp, (void*)&hbp, (void*)&outp, (void*)&arrp,
      (void*)&b_ii, (void*)&b_hi, (void*)&b_if, (void*)&b_hf,
      (void*)&b_ig, (void*)&b_hg, (void*)&b_io, (void*)&b_ho};
  hipLaunchCooperativeKernel((const void*)k_lstm, dim3(NBL), dim3(512), args, 0, stream);
}

// Round 9
// 5209.370 us; speedup vs baseline: 1.4857x; 1.4857x over previous
//
#include <hip/hip_runtime.h>
#include <cstdint>
#include <cstddef>
#include <string.h>

typedef __bf16 bf16;
typedef bf16 bf16x4 __attribute__((ext_vector_type(4)));
typedef bf16 bf16x8 __attribute__((ext_vector_type(8)));
typedef float f32x4 __attribute__((ext_vector_type(4)));
typedef unsigned long long u64;

#define B_   64
#define T_   512
#define I_   1024
#define H_   1024
#define BT_  32768
#define NBL  64    // lstm blocks
#define NJ   16    // hidden units per lstm block

// ---- ws layout (bytes) ----
#define WS_XBF   ((size_t)0              )  // x as bf16 [32768][1024]            : 67108864
#define WS_WXP   ((size_t)67108864)       // Wx^T bf16 [4096][1024]             : 8388608
#define WS_WHP   ((size_t)75497472)       // Wh packed bf16 [64][128][64][8]    : 8388608
#define WS_XG    ((size_t)83886080)       // xg bf16 [512][64][64][64]          : 268435456
#define WS_HB    ((size_t)352321536)      // h dbuf bf16 [2][64][1024]          : 262144
#define WS_ARR   ((size_t)352583680)      // flags u32[4 rowgrp][64 blk]        : 8192
#define WS_NEED  ((size_t)352600064)

#define GLD_LDS16(gptr, lptr) \
  __builtin_amdgcn_global_load_lds((const __attribute__((address_space(1))) void*)(gptr), \
                                   (__attribute__((address_space(3))) void*)(lptr), 16, 0, 0)

__device__ __forceinline__ float sigmoidf_(float x) { return 1.0f / (1.0f + __expf(-x)); }
// branch-free tanh: 1 - 2/(e^{2x}+1); saturates correctly for |x| large (no NaN).
__device__ __forceinline__ float tanhf_(float x) { float e = __expf(2.0f * x); return 1.0f - 2.0f / (e + 1.0f); }
__device__ __forceinline__ float lo2f(unsigned u) { unsigned v = u << 16; float f; memcpy(&f, &v, 4); return f; }
__device__ __forceinline__ float hi2f(unsigned u) { unsigned v = u & 0xffff0000u; float f; memcpy(&f, &v, 4); return f; }
__device__ __forceinline__ unsigned short b2s(bf16 h) { unsigned short s; memcpy(&s, &h, 2); return s; }

// ---------------- pack kernels ----------------

__global__ __launch_bounds__(256) void k_cvt_x(const float4* __restrict__ in,
                                               bf16* __restrict__ out, int n4) {
  int i = blockIdx.x * blockDim.x + threadIdx.x;
  int stride = gridDim.x * blockDim.x;
  for (; i < n4; i += stride) {
    float4 v = in[i];
    bf16x4 r = { (bf16)v.x, (bf16)v.y, (bf16)v.z, (bf16)v.w };
    *(bf16x4*)(out + (size_t)i * 4) = r;
  }
}

// Wx^T: wxp[(gate*1024 + n)][k] = W[k][n]   (32x32 LDS tile transpose)
__global__ __launch_bounds__(256) void k_pack_wx(const float* __restrict__ W,
                                                 bf16* __restrict__ wxp, int gate) {
  __shared__ bf16 tile[32][33];
  int bx = blockIdx.x & 31, by = blockIdx.x >> 5;
  int tx = threadIdx.x & 31, ty = threadIdx.x >> 5;
  int k0 = by * 32, n0 = bx * 32;
  for (int r = 0; r < 32; r += 8)
    tile[ty + r][tx] = (bf16)W[(size_t)(k0 + ty + r) * H_ + n0 + tx];
  __syncthreads();
  for (int r = 0; r < 32; r += 8)
    wxp[(size_t)(gate * H_ + n0 + ty + r) * I_ + k0 + tx] = tile[tx][ty + r];
}

// Wh packed GATE-MAJOR (R7 layout): whp[blk][k>>3][gate*16 + (u&15)][k&7] = W[k][u]
__global__ __launch_bounds__(256) void k_pack_wh(const float* __restrict__ W,
                                                 bf16* __restrict__ whp, int gate) {
  __shared__ bf16 tile[32][33];
  int bx = blockIdx.x & 31, by = blockIdx.x >> 5;
  int tx = threadIdx.x & 31, ty = threadIdx.x >> 5;
  int k0 = by * 32, u0 = bx * 32;
  for (int r = 0; r < 32; r += 8)
    tile[ty + r][tx] = (bf16)W[(size_t)(k0 + ty + r) * H_ + u0 + tx];
  __syncthreads();
  for (int r = 0; r < 32; r += 8) {
    int u = u0 + ty + r;
    int k = k0 + tx;
    size_t addr = ((size_t)(u >> 4) * 128 + (k >> 3)) * 512 +
                  (size_t)(gate * 16 + (u & 15)) * 8 + (k & 7);
    whp[addr] = tile[tx][ty + r];
  }
}

// ---------------- phase 1: xg = x @ Wx  (bf16 MFMA, m97-style) ----------------
// xg written UNIT-MAJOR: xg[t][blk][row][ (u&15)*4 + gate ]
__global__ __launch_bounds__(256) void k_gemm_xg(const bf16* __restrict__ A,
                                                 const bf16* __restrict__ Bt,
                                                 bf16* __restrict__ xg) {
  __shared__ bf16 As[128 * 64];
  __shared__ bf16 Bs[128 * 64];
  int bid = blockIdx.x;
  int bm = bid >> 5, bn = bid & 31;
  int m0 = bm * 128, n0 = bn * 128;
  int tid = threadIdx.x, lane = tid & 63, w = tid >> 6;
  int lr = lane & 15, lk = lane >> 4;
  int sr = lane >> 3, sk = (lane & 7) * 8;
  int wm = (w >> 1) * 64, wn = (w & 1) * 64;
  f32x4 acc[4][4] = {};

  for (int k0 = 0; k0 < 1024; k0 += 64) {
    __syncthreads();
    for (int i = 0; i < 4; ++i) {
      int idx = w * 4 + i;
      const bf16* ga = A + (size_t)(m0 + idx * 8 + sr) * 1024 + k0 + sk;
      GLD_LDS16(ga, &As[idx * 512]);
      const bf16* gb = Bt + (size_t)(n0 + idx * 8 + sr) * 1024 + k0 + sk;
      GLD_LDS16(gb, &Bs[idx * 512]);
    }
    asm volatile("s_waitcnt vmcnt(0)" ::: "memory");
    __syncthreads();
#pragma unroll
    for (int kk = 0; kk < 64; kk += 32) {
      bf16x8 af[4], bfr[4];
#pragma unroll
      for (int i = 0; i < 4; ++i)
        af[i] = *(const bf16x8*)&As[(wm + i * 16 + lr) * 64 + kk + lk * 8];
#pragma unroll
      for (int j = 0; j < 4; ++j)
        bfr[j] = *(const bf16x8*)&Bs[(wn + j * 16 + lr) * 64 + kk + lk * 8];
#pragma unroll
      for (int i = 0; i < 4; ++i)
#pragma unroll
        for (int j = 0; j < 4; ++j)
          acc[i][j] = __builtin_amdgcn_mfma_f32_16x16x32_bf16(af[i], bfr[j], acc[i][j], 0, 0, 0);
    }
  }
  // epilogue: scatter into xg[t][blk][b][c],  blk = u>>4, c = (u&15)*4 + g
#pragma unroll
  for (int i = 0; i < 4; ++i) {
#pragma unroll
    for (int j = 0; j < 4; ++j) {
      int n = n0 + wn + j * 16 + lr;
      int u = n & 1023, g = n >> 10;
      int blk = u >> 4, c = (u & 15) * 4 + g;
      int mb = m0 + wm + i * 16 + lk * 4;
#pragma unroll
      for (int r = 0; r < 4; ++r) {
        int m = mb + r;
        int t = m & 511, bb = m >> 9;
        xg[(((size_t)t * NBL + blk) * B_ + bb) * 64 + c] = (bf16)acc[i][j][r];
      }
    }
  }
}

// ---------------- phase 2: persistent LSTM scan, zero-syncthreads dataflow ----------------
// 64 blocks x 256 threads (4 waves). Block owns 16 units; wave = 16-row group, FULL K,
// all 64 gate-cols (gate-major c=g*16+u) -> lane directly owns acc[gate][r] for
// (row = rg*16 + lk*4 + r, unit = lr): no transpose, no cross-wave reduction, no
// __syncthreads in steady state. Publishes: 16 lanes x 2B contiguous = one 32B sector
// per (lk,r) -> fully sector-coalesced (fixes R8's 4x write amplification).
// 4 independent row-chains; per-wave flags after per-wave vmcnt-0 drain.
__global__ __launch_bounds__(256) void k_lstm(const bf16* __restrict__ xg,
                                              const bf16* __restrict__ whp,
                                              bf16* hb,              // [2][64][1024]
                                              float* __restrict__ out,
                                              unsigned* arr,         // [4 rowgrp][64 blk] u32
                                              const float* __restrict__ bii, const float* __restrict__ bhi,
                                              const float* __restrict__ bif, const float* __restrict__ bhf,
                                              const float* __restrict__ big, const float* __restrict__ bhg,
                                              const float* __restrict__ bio, const float* __restrict__ bho) {
  __shared__ bf16 whl[65536];          // 128 KB: [k>>3][c][k&7], c = g*16+u
  int blk = blockIdx.x;
  int tid = threadIdx.x;
  int lane = tid & 63, rg = tid >> 6;  // wave = row-group
  int lr = lane & 15, lk = lane >> 4;

  {  // stage Wh slice: 128KB contiguous, 256 threads x 32 iters
    const bf16* src = whp + (size_t)blk * 65536;
#pragma unroll
    for (int i = 0; i < 32; ++i)
      *(bf16x8*)&whl[(size_t)(i * 256 + tid) * 8] = *(const bf16x8*)&src[(size_t)(i * 256 + tid) * 8];
  }

  // lane ownership: unit lr (in-block), rows rg*16 + lk*4 + r
  int ug = blk * NJ + lr;
  f32x4 bias = { bii[ug] + bhi[ug], bif[ug] + bhf[ug],
                 big[ug] + bhg[ug], bio[ug] + bho[ug] };
  float cs[4] = {0.f, 0.f, 0.f, 0.f};

  const char* hb_c = (const char*)hb;
  const char* flg = (const char*)arr;
  __syncthreads();  // whl ready (only block barrier in the kernel)

  for (int t = 0; t < T_; ++t) {
    // ---- poll: flags of all 64 producer blocks at my rowgrp >= t ----
    if (t > 0) {
      const char* fp = flg + ((size_t)rg * 64 + lane) * 4;
      unsigned fv; int cap = 0;
      do {
        asm volatile("global_load_dword %0, %1, off sc0 sc1\n\ts_waitcnt vmcnt(0)"
                     : "=v"(fv) : "v"(fp) : "memory");
      } while (!__all((int)(fv >= (unsigned)t)) && ++cap < 300000);
      __builtin_amdgcn_sched_barrier(0);
    }

    // ---- issue 32 A-loads (full K for my 16 rows), then 4 xg loads ----
    bf16x8 af[32];
    const char* hbase = hb_c + (size_t)(t & 1) * 131072 +
                        (size_t)(rg * 16 + lr) * 2048 + (size_t)lk * 16;
#pragma unroll
    for (int i = 0; i < 32; ++i)
      asm volatile("global_load_dwordx4 %0, %1, off sc0 sc1"
                   : "=v"(af[i]) : "v"(hbase + (size_t)i * 64));
    u64 xq[4];
    {
      const char* xb = (const char*)xg + (((size_t)t * NBL + blk) * B_ + rg * 16 + lk * 4) * 128 +
                       (size_t)lr * 8;
#pragma unroll
      for (int r = 0; r < 4; ++r)
        asm volatile("global_load_dwordx2 %0, %1, off" : "=v"(xq[r]) : "v"(xb + (size_t)r * 128));
    }

    // ---- MFMA: 32 ksteps x 4 gate-tiles, vmcnt-gated groups of 8 (36 in flight) ----
    f32x4 acc[4] = {};
#define MFMA_GRP(G)                                                                        \
    _Pragma("unroll")                                                                      \
    for (int ii = 0; ii < 8; ++ii) {                                                       \
      int i = (G) * 8 + ii;                                                                \
      _Pragma("unroll")                                                                    \
      for (int nt = 0; nt < 4; ++nt) {                                                     \
        bf16x8 bb = *(const bf16x8*)&whl[((i * 4 + lk) * 64 + nt * 16 + lr) * 8];          \
        acc[nt] = __builtin_amdgcn_mfma_f32_16x16x32_bf16(af[i], bb, acc[nt], 0, 0, 0);    \
      }                                                                                    \
    }
    asm volatile("s_waitcnt vmcnt(28)" ::: "memory");
    __builtin_amdgcn_sched_barrier(0);
    MFMA_GRP(0)
    asm volatile("s_waitcnt vmcnt(20)" ::: "memory");
    __builtin_amdgcn_sched_barrier(0);
    MFMA_GRP(1)
    asm volatile("s_waitcnt vmcnt(12)" ::: "memory");
    __builtin_amdgcn_sched_barrier(0);
    MFMA_GRP(2)
    asm volatile("s_waitcnt vmcnt(4)" ::: "memory");
    __builtin_amdgcn_sched_barrier(0);
    MFMA_GRP(3)
#undef MFMA_GRP
    asm volatile("s_waitcnt vmcnt(0)" ::: "memory");   // xg landed
    __builtin_amdgcn_sched_barrier(0);

    // ---- gates + state update: acc[g][r] is complete; 4 rows x 1 unit per lane ----
    float hv[4];
#pragma unroll
    for (int r = 0; r < 4; ++r) {
      unsigned xlo = (unsigned)xq[r], xhi = (unsigned)(xq[r] >> 32);
      float gi = acc[0][r] + lo2f(xlo) + bias[0];
      float gf = acc[1][r] + hi2f(xlo) + bias[1];
      float gg = acc[2][r] + lo2f(xhi) + bias[2];
      float go = acc[3][r] + hi2f(xhi) + bias[3];
      cs[r] = sigmoidf_(gf) * cs[r] + sigmoidf_(gi) * tanhf_(gg);
      hv[r] = sigmoidf_(go) * tanhf_(cs[r]);
    }

    if (t == T_ - 1) {
#pragma unroll
      for (int r = 0; r < 4; ++r) {
        int grow = rg * 16 + lk * 4 + r;
        out[(size_t)grow * H_ + ug] = hv[r];
        out[(size_t)B_ * H_ + (size_t)grow * H_ + ug] = cs[r];
      }
      break;
    }

    // ---- publish h(t+1): 16 lanes x 2B contiguous per (lk,r) = one 32B sector ----
    {
      const char* hn = hb_c + (size_t)((t + 1) & 1) * 131072;
#pragma unroll
      for (int r = 0; r < 4; ++r) {
        unsigned hbv = (unsigned)b2s((bf16)hv[r]);
        const char* pa = hn + (size_t)(rg * 16 + lk * 4 + r) * 2048 + (size_t)ug * 2;
        asm volatile("global_store_short %0, %1, off sc0 sc1" :: "v"(pa), "v"(hbv) : "memory");
      }
    }

    // ---- per-wave drain + arm own flag (no block-wide sync) ----
    asm volatile("s_waitcnt vmcnt(0)" ::: "memory");
    if (lane == 0) {
      unsigned tv = (unsigned)(t + 1);
      const char* fa = flg + ((size_t)rg * 64 + blk) * 4;
      asm volatile("global_store_dword %0, %1, off sc0 sc1" :: "v"(fa), "v"(tv) : "memory");
    }
  }
}

// ---------------- launcher ----------------

extern "C" void kernel_launch(void* const* d_in, const int* in_sizes, int n_in,
                              void* d_out, int out_size, void* d_ws, size_t ws_size,
                              hipStream_t stream) {
  if (ws_size < WS_NEED) return;

  const float* x = (const float*)d_in[0];
  const float* W_ii = (const float*)d_in[1];
  const float* W_hi = (const float*)d_in[2];
  const float* W_if = (const float*)d_in[3];
  const float* W_hf = (const float*)d_in[4];
  const float* W_ig = (const float*)d_in[5];
  const float* W_hg = (const float*)d_in[6];
  const float* W_io = (const float*)d_in[7];
  const float* W_ho = (const float*)d_in[8];
  const float* b_ii = (const float*)d_in[9];
  const float* b_hi = (const float*)d_in[10];
  const float* b_if = (const float*)d_in[11];
  const float* b_hf = (const float*)d_in[12];
  const float* b_ig = (const float*)d_in[13];
  const float* b_hg = (const float*)d_in[14];
  const float* b_io = (const float*)d_in[15];
  const float* b_ho = (const float*)d_in[16];

  char* ws = (char*)d_ws;
  bf16* xbf = (bf16*)(ws + WS_XBF);
  bf16* wxp = (bf16*)(ws + WS_WXP);
  bf16* whp = (bf16*)(ws + WS_WHP);
  bf16* xgp = (bf16*)(ws + WS_XG);
  bf16* hbp = (bf16*)(ws + WS_HB);
  unsigned* arrp = (unsigned*)(ws + WS_ARR);
  float* outp = (float*)d_out;

  // zero h0 buffers + flags (contiguous region)
  hipMemsetAsync(ws + WS_HB, 0, 262144 + 8192, stream);

  // pack
  k_cvt_x<<<2048, 256, 0, stream>>>((const float4*)x, xbf, BT_ * I_ / 4);
  const float* wx_g[4] = {W_ii, W_if, W_ig, W_io};
  const float* wh_g[4] = {W_hi, W_hf, W_hg, W_ho};
  for (int g = 0; g < 4; ++g) {
    k_pack_wx<<<1024, 256, 0, stream>>>(wx_g[g], wxp, g);
    k_pack_wh<<<1024, 256, 0, stream>>>(wh_g[g], whp, g);
  }

  // phase 1 GEMM
  k_gemm_xg<<<dim3(256 * 32), 256, 0, stream>>>(xbf, wxp, xgp);

  // phase 2 cooperative scan: 64 blocks x 256 threads
  void* args[] = {
      (void*)&xgp, (void*)&whp, (void*)&hbp, (void*)&outp, (void*)&arrp,
      (void*)&b_ii, (void*)&b_hi, (void*)&b_if, (void*)&b_hf,
      (void*)&b_ig, (void*)&b_hg, (void*)&b_io, (void*)&b_ho};
  hipLaunchCooperativeKernel((const void*)k_lstm, dim3(NBL), dim3(256), args, 0, stream);
}

// Round 10
// 4199.332 us; speedup vs baseline: 1.8431x; 1.2405x over previous
//
#include <hip/hip_runtime.h>
#include <cstdint>
#include <cstddef>
#include <string.h>

typedef __bf16 bf16;
typedef bf16 bf16x4 __attribute__((ext_vector_type(4)));
typedef bf16 bf16x8 __attribute__((ext_vector_type(8)));
typedef float f32x4 __attribute__((ext_vector_type(4)));
typedef unsigned long long u64;

#define B_   64
#define T_   512
#define I_   1024
#define H_   1024
#define BT_  32768
#define NBL  64    // lstm blocks
#define NJ   16    // hidden units per lstm block

// ---- ws layout (bytes) ----
#define WS_XBF   ((size_t)0)              // x as bf16 [32768][1024]            : 67108864
#define WS_WXP   ((size_t)67108864)       // Wx^T bf16 [4096][1024]             : 8388608
#define WS_WHP   ((size_t)75497472)       // Wh packed bf16 [64][128][64][8]    : 8388608
#define WS_XG    ((size_t)83886080)       // xg bf16 [512][64][64][64]          : 268435456
#define WS_HB    ((size_t)352321536)      // h dbuf bf16 [2][64][1024]          : 262144
#define WS_ARR   ((size_t)352583680)      // flags u32[4 rowgrp][64 blk] @64B   : 16384
#define WS_NEED  ((size_t)352600064)

#define GLD_LDS16(gptr, lptr) \
  __builtin_amdgcn_global_load_lds((const __attribute__((address_space(1))) void*)(gptr), \
                                   (__attribute__((address_space(3))) void*)(lptr), 16, 0, 0)

__device__ __forceinline__ float sigmoidf_(float x) { return 1.0f / (1.0f + __expf(-x)); }
// branch-free tanh: 1 - 2/(e^{2x}+1); saturates correctly for |x| large (no NaN).
__device__ __forceinline__ float tanhf_(float x) { float e = __expf(2.0f * x); return 1.0f - 2.0f / (e + 1.0f); }
__device__ __forceinline__ float lo2f(unsigned u) { unsigned v = u << 16; float f; memcpy(&f, &v, 4); return f; }
__device__ __forceinline__ float hi2f(unsigned u) { unsigned v = u & 0xffff0000u; float f; memcpy(&f, &v, 4); return f; }
__device__ __forceinline__ unsigned short b2s(bf16 h) { unsigned short s; memcpy(&s, &h, 2); return s; }

// ---------------- pack kernels ----------------

__global__ __launch_bounds__(256) void k_cvt_x(const float4* __restrict__ in,
                                               bf16* __restrict__ out, int n4) {
  int i = blockIdx.x * blockDim.x + threadIdx.x;
  int stride = gridDim.x * blockDim.x;
  for (; i < n4; i += stride) {
    float4 v = in[i];
    bf16x4 r = { (bf16)v.x, (bf16)v.y, (bf16)v.z, (bf16)v.w };
    *(bf16x4*)(out + (size_t)i * 4) = r;
  }
}

// Wx^T: wxp[(gate*1024 + n)][k] = W[k][n]   (32x32 LDS tile transpose)
__global__ __launch_bounds__(256) void k_pack_wx(const float* __restrict__ W,
                                                 bf16* __restrict__ wxp, int gate) {
  __shared__ bf16 tile[32][33];
  int bx = blockIdx.x & 31, by = blockIdx.x >> 5;
  int tx = threadIdx.x & 31, ty = threadIdx.x >> 5;
  int k0 = by * 32, n0 = bx * 32;
  for (int r = 0; r < 32; r += 8)
    tile[ty + r][tx] = (bf16)W[(size_t)(k0 + ty + r) * H_ + n0 + tx];
  __syncthreads();
  for (int r = 0; r < 32; r += 8)
    wxp[(size_t)(gate * H_ + n0 + ty + r) * I_ + k0 + tx] = tile[tx][ty + r];
}

// Wh packed GATE-MAJOR: whp[blk][k>>3][gate*16 + (u&15)][k&7] = W[k][u]
__global__ __launch_bounds__(256) void k_pack_wh(const float* __restrict__ W,
                                                 bf16* __restrict__ whp, int gate) {
  __shared__ bf16 tile[32][33];
  int bx = blockIdx.x & 31, by = blockIdx.x >> 5;
  int tx = threadIdx.x & 31, ty = threadIdx.x >> 5;
  int k0 = by * 32, u0 = bx * 32;
  for (int r = 0; r < 32; r += 8)
    tile[ty + r][tx] = (bf16)W[(size_t)(k0 + ty + r) * H_ + u0 + tx];
  __syncthreads();
  for (int r = 0; r < 32; r += 8) {
    int u = u0 + ty + r;
    int k = k0 + tx;
    size_t addr = ((size_t)(u >> 4) * 128 + (k >> 3)) * 512 +
                  (size_t)(gate * 16 + (u & 15)) * 8 + (k & 7);
    whp[addr] = tile[tx][ty + r];
  }
}

// ---------------- phase 1: xg = x @ Wx  (bf16 MFMA, m97-style) ----------------
// xg written UNIT-MAJOR: xg[t][blk][row][ (u&15)*4 + gate ]
__global__ __launch_bounds__(256) void k_gemm_xg(const bf16* __restrict__ A,
                                                 const bf16* __restrict__ Bt,
                                                 bf16* __restrict__ xg) {
  __shared__ bf16 As[128 * 64];
  __shared__ bf16 Bs[128 * 64];
  int bid = blockIdx.x;
  int bm = bid >> 5, bn = bid & 31;
  int m0 = bm * 128, n0 = bn * 128;
  int tid = threadIdx.x, lane = tid & 63, w = tid >> 6;
  int lr = lane & 15, lk = lane >> 4;
  int sr = lane >> 3, sk = (lane & 7) * 8;
  int wm = (w >> 1) * 64, wn = (w & 1) * 64;
  f32x4 acc[4][4] = {};

  for (int k0 = 0; k0 < 1024; k0 += 64) {
    __syncthreads();
    for (int i = 0; i < 4; ++i) {
      int idx = w * 4 + i;
      const bf16* ga = A + (size_t)(m0 + idx * 8 + sr) * 1024 + k0 + sk;
      GLD_LDS16(ga, &As[idx * 512]);
      const bf16* gb = Bt + (size_t)(n0 + idx * 8 + sr) * 1024 + k0 + sk;
      GLD_LDS16(gb, &Bs[idx * 512]);
    }
    asm volatile("s_waitcnt vmcnt(0)" ::: "memory");
    __syncthreads();
#pragma unroll
    for (int kk = 0; kk < 64; kk += 32) {
      bf16x8 af[4], bfr[4];
#pragma unroll
      for (int i = 0; i < 4; ++i)
        af[i] = *(const bf16x8*)&As[(wm + i * 16 + lr) * 64 + kk + lk * 8];
#pragma unroll
      for (int j = 0; j < 4; ++j)
        bfr[j] = *(const bf16x8*)&Bs[(wn + j * 16 + lr) * 64 + kk + lk * 8];
#pragma unroll
      for (int i = 0; i < 4; ++i)
#pragma unroll
        for (int j = 0; j < 4; ++j)
          acc[i][j] = __builtin_amdgcn_mfma_f32_16x16x32_bf16(af[i], bfr[j], acc[i][j], 0, 0, 0);
    }
  }
  // epilogue: scatter into xg[t][blk][b][c],  blk = u>>4, c = (u&15)*4 + g
#pragma unroll
  for (int i = 0; i < 4; ++i) {
#pragma unroll
    for (int j = 0; j < 4; ++j) {
      int n = n0 + wn + j * 16 + lr;
      int u = n & 1023, g = n >> 10;
      int blk = u >> 4, c = (u & 15) * 4 + g;
      int mb = m0 + wm + i * 16 + lk * 4;
#pragma unroll
      for (int r = 0; r < 4; ++r) {
        int m = mb + r;
        int t = m & 511, bb = m >> 9;
        xg[(((size_t)t * NBL + blk) * B_ + bb) * 64 + c] = (bf16)acc[i][j][r];
      }
    }
  }
}

// ---------------- phase 2: persistent cooperative LSTM scan (R7 + kh1-owned gates) ----------------
// 64 blocks x 512 threads (8 waves, 2/SIMD). Wave = (wm rowgrp16, kh K-half).
// Gate-major whl: kh wave's acc[nt][r] = kh-partial of (row wm+lk*4+r, unit lr, gate nt).
// kh0 writes partials to gl; ONE sync; kh1 reads gl + its registers -> complete gates,
// publishes h rows (32B sectors), drains, arms per-(rowgrp,blk) flag. Second sync only
// guards gl reuse. Consumers poll exactly their 32 producer flags (per K-half).
__global__ __launch_bounds__(512) void k_lstm(const bf16* __restrict__ xg,
                                              const bf16* __restrict__ whp,
                                              bf16* hb,              // [2][64][1024]
                                              float* __restrict__ out,
                                              unsigned* arr,         // [4 rowgrp][64 blk] @64B
                                              const float* __restrict__ bii, const float* __restrict__ bhi,
                                              const float* __restrict__ bif, const float* __restrict__ bhf,
                                              const float* __restrict__ big, const float* __restrict__ bhg,
                                              const float* __restrict__ bio, const float* __restrict__ bho) {
  __shared__ bf16 whl[65536];          // 128 KB: [k>>3][c][k&7], c = g*16+u
  __shared__ float gl[64 * 65];        // kh0 partials, padded rows
  int blk = blockIdx.x;
  int tid = threadIdx.x;
  int lane = tid & 63, w = tid >> 6;
  int lr = lane & 15, lk = lane >> 4;
  int wm = (w >> 1) * 16;   // row-group (16 batch rows)
  int kh = w & 1;           // K half

  {  // stage Wh slice: 128KB contiguous
    const bf16* src = whp + (size_t)blk * 65536;
#pragma unroll
    for (int i = 0; i < 16; ++i)
      *(bf16x8*)&whl[(size_t)(i * 512 + tid) * 8] = *(const bf16x8*)&src[(size_t)(i * 512 + tid) * 8];
  }

  int ug = blk * NJ + lr;              // unit owned by this lane (gates, kh1)
  f32x4 bias = { bii[ug] + bhi[ug], bif[ug] + bhf[ug],
                 big[ug] + bhg[ug], bio[ug] + bho[ug] };
  float cs[4] = {0.f, 0.f, 0.f, 0.f};

  const char* hb_c = (const char*)hb;
  const char* flg = (const char*)arr;
  __syncthreads();  // whl ready

  for (int t = 0; t < T_; ++t) {
    // ---- poll: my 32 K-half producers' rowgrp flags >= t ----
    if (t > 0) {
      const char* fp = flg + ((size_t)(wm >> 4) * 64 + kh * 32 + (lane & 31)) * 64;
      unsigned fv; int cap = 0;
      do {
        asm volatile("global_load_dword %0, %1, off sc0 sc1\n\ts_waitcnt vmcnt(0)"
                     : "=v"(fv) : "v"(fp) : "memory");
      } while (!__all((int)(fv >= (unsigned)t)) && ++cap < 300000);
      __builtin_amdgcn_sched_barrier(0);
    }

    // ---- issue 16 A-loads (my rows, my K-half) + 4 xg loads (uniform bookkeeping) ----
    bf16x8 af[16];
    const char* hbase = hb_c + (size_t)(t & 1) * 131072 + (size_t)(wm + lr) * 2048 +
                        (size_t)kh * 1024 + (size_t)lk * 16;
#pragma unroll
    for (int i = 0; i < 16; ++i)
      asm volatile("global_load_dwordx4 %0, %1, off sc0 sc1"
                   : "=v"(af[i]) : "v"(hbase + (size_t)i * 64));
    u64 xq[4];
    {
      const char* xb = (const char*)xg + (((size_t)t * NBL + blk) * B_ + wm + lk * 4) * 128 +
                       (size_t)lr * 8;
#pragma unroll
      for (int r = 0; r < 4; ++r)
        asm volatile("global_load_dwordx2 %0, %1, off" : "=v"(xq[r]) : "v"(xb + (size_t)r * 128));
    }

    // ---- GEMM: 4 vmcnt-gated groups of 4 ksteps x 4 gate-tiles ----
    f32x4 acc[4] = {};
#define MFMA_GRP(G)                                                                        \
    _Pragma("unroll")                                                                      \
    for (int ii = 0; ii < 4; ++ii) {                                                       \
      int i = (G) * 4 + ii;                                                                \
      int kg = kh * 64 + i * 4 + lk;                                                       \
      _Pragma("unroll")                                                                    \
      for (int nt = 0; nt < 4; ++nt) {                                                     \
        bf16x8 bb = *(const bf16x8*)&whl[(kg * 64 + nt * 16 + lr) * 8];                    \
        acc[nt] = __builtin_amdgcn_mfma_f32_16x16x32_bf16(af[i], bb, acc[nt], 0, 0, 0);    \
      }                                                                                    \
    }
    asm volatile("s_waitcnt vmcnt(16)" ::: "memory");
    __builtin_amdgcn_sched_barrier(0);
    MFMA_GRP(0)
    asm volatile("s_waitcnt vmcnt(12)" ::: "memory");
    __builtin_amdgcn_sched_barrier(0);
    MFMA_GRP(1)
    asm volatile("s_waitcnt vmcnt(8)" ::: "memory");
    __builtin_amdgcn_sched_barrier(0);
    MFMA_GRP(2)
    asm volatile("s_waitcnt vmcnt(4)" ::: "memory");
    __builtin_amdgcn_sched_barrier(0);
    MFMA_GRP(3)
#undef MFMA_GRP

    // ---- kh0: deposit partials in gl ----
    int grow = wm + lk * 4;
    if (kh == 0) {
#pragma unroll
      for (int nt = 0; nt < 4; ++nt)
#pragma unroll
        for (int r = 0; r < 4; ++r)
          gl[(grow + r) * 65 + nt * 16 + lr] = acc[nt][r];
    }
    __syncthreads();   // sync#1: gl partials visible

    if (kh == 1) {
      asm volatile("s_waitcnt vmcnt(0)" ::: "memory");   // xq landed
      __builtin_amdgcn_sched_barrier(0);
      // complete gates: gl (kh0) + acc (kh1 registers)
      float hv[4];
#pragma unroll
      for (int r = 0; r < 4; ++r) {
        unsigned xlo = (unsigned)xq[r], xhi = (unsigned)(xq[r] >> 32);
        float gi = gl[(grow + r) * 65 + lr]      + acc[0][r] + lo2f(xlo) + bias[0];
        float gf = gl[(grow + r) * 65 + 16 + lr] + acc[1][r] + hi2f(xlo) + bias[1];
        float gg = gl[(grow + r) * 65 + 32 + lr] + acc[2][r] + lo2f(xhi) + bias[2];
        float go = gl[(grow + r) * 65 + 48 + lr] + acc[3][r] + hi2f(xhi) + bias[3];
        cs[r] = sigmoidf_(gf) * cs[r] + sigmoidf_(gi) * tanhf_(gg);
        hv[r] = sigmoidf_(go) * tanhf_(cs[r]);
      }

      if (t == T_ - 1) {
#pragma unroll
        for (int r = 0; r < 4; ++r) {
          out[(size_t)(grow + r) * H_ + ug] = hv[r];
          out[(size_t)B_ * H_ + (size_t)(grow + r) * H_ + ug] = cs[r];
        }
      } else {
        // publish h(t+1): 16 lanes x 2B contiguous per row = one 32B sector
        const char* hn = hb_c + (size_t)((t + 1) & 1) * 131072;
#pragma unroll
        for (int r = 0; r < 4; ++r) {
          unsigned hbv = (unsigned)b2s((bf16)hv[r]);
          const char* pa = hn + (size_t)(grow + r) * 2048 + (size_t)ug * 2;
          asm volatile("global_store_short %0, %1, off sc0 sc1" :: "v"(pa), "v"(hbv) : "memory");
        }
        // per-wave drain + arm rowgrp flag (consumers unblock without block tail)
        asm volatile("s_waitcnt vmcnt(0)" ::: "memory");
        if (lane == 0) {
          unsigned tv = (unsigned)(t + 1);
          const char* fa = flg + ((size_t)(wm >> 4) * 64 + blk) * 64;
          asm volatile("global_store_dword %0, %1, off sc0 sc1" :: "v"(fa), "v"(tv) : "memory");
        }
      }
    }

    if (t == T_ - 1) break;            // uniform: all waves exit before sync#2
    __syncthreads();                   // sync#2: gl safe to overwrite next step
  }
}

// ---------------- launcher ----------------

extern "C" void kernel_launch(void* const* d_in, const int* in_sizes, int n_in,
                              void* d_out, int out_size, void* d_ws, size_t ws_size,
                              hipStream_t stream) {
  if (ws_size < WS_NEED) return;

  const float* x = (const float*)d_in[0];
  const float* W_ii = (const float*)d_in[1];
  const float* W_hi = (const float*)d_in[2];
  const float* W_if = (const float*)d_in[3];
  const float* W_hf = (const float*)d_in[4];
  const float* W_ig = (const float*)d_in[5];
  const float* W_hg = (const float*)d_in[6];
  const float* W_io = (const float*)d_in[7];
  const float* W_ho = (const float*)d_in[8];
  const float* b_ii = (const float*)d_in[9];
  const float* b_hi = (const float*)d_in[10];
  const float* b_if = (const float*)d_in[11];
  const float* b_hf = (const float*)d_in[12];
  const float* b_ig = (const float*)d_in[13];
  const float* b_hg = (const float*)d_in[14];
  const float* b_io = (const float*)d_in[15];
  const float* b_ho = (const float*)d_in[16];

  char* ws = (char*)d_ws;
  bf16* xbf = (bf16*)(ws + WS_XBF);
  bf16* wxp = (bf16*)(ws + WS_WXP);
  bf16* whp = (bf16*)(ws + WS_WHP);
  bf16* xgp = (bf16*)(ws + WS_XG);
  bf16* hbp = (bf16*)(ws + WS_HB);
  unsigned* arrp = (unsigned*)(ws + WS_ARR);
  float* outp = (float*)d_out;

  // zero h0 buffers + flags (contiguous region)
  hipMemsetAsync(ws + WS_HB, 0, 262144 + 16384, stream);

  // pack
  k_cvt_x<<<2048, 256, 0, stream>>>((const float4*)x, xbf, BT_ * I_ / 4);
  const float* wx_g[4] = {W_ii, W_if, W_ig, W_io};
  const float* wh_g[4] = {W_hi, W_hf, W_hg, W_ho};
  for (int g = 0; g < 4; ++g) {
    k_pack_wx<<<1024, 256, 0, stream>>>(wx_g[g], wxp, g);
    k_pack_wh<<<1024, 256, 0, stream>>>(wh_g[g], whp, g);
  }

  // phase 1 GEMM
  k_gemm_xg<<<dim3(256 * 32), 256, 0, stream>>>(xbf, wxp, xgp);

  // phase 2 cooperative scan: 64 blocks x 512 threads
  void* args[] = {
      (void*)&xgp, (void*)&whp, (void*)&hbp, (void*)&outp, (void*)&arrp,
      (void*)&b_ii, (void*)&b_hi, (void*)&b_if, (void*)&b_hf,
      (void*)&b_ig, (void*)&b_hg, (void*)&b_io, (void*)&b_ho};
  hipLaunchCooperativeKernel((const void*)k_lstm, dim3(NBL), dim3(512), args, 0, stream);
}